// Round 3
// baseline (629.695 us; speedup 1.0000x reference)
//
#include <hip/hip_runtime.h>
#include <hip/hip_bf16.h>
#include <cstdint>

typedef unsigned short ushort_t;

__device__ __forceinline__ float softplusf(float x){
    return fmaxf(x, 0.f) + log1pf(__expf(-fabsf(x)));
}
__device__ __forceinline__ float siluf(float x){
    return x / (1.f + __expf(-x));
}
__device__ __forceinline__ float b2f(ushort_t u){
    union { uint32_t i; float f; } v; v.i = ((uint32_t)u)<<16; return v.f;
}
__device__ __forceinline__ ushort_t f2b(float f){
    uint32_t x = __float_as_uint(f);
    uint32_t r = (x + 0x7FFFu + ((x>>16)&1u)) >> 16;
    return (ushort_t)r;
}

struct AxialParams {
    const float* kh[3]; const float* kw[3]; const float* k3[3];
    const float* g[3];  const float* b[3];
};

// ---- K1: axial depthwise chain (kw -> kh -> 3x3) + BN + residual (f32 in, f32 out) ----
__global__ __launch_bounds__(256) void k_axial(const float* __restrict__ x,
                                               float* __restrict__ Y0, AxialParams P){
    __shared__ float s0[4096];
    __shared__ float s1[4096];
    int bid = blockIdx.x;
    int i = bid >> 8;            // branch
    int rem = bid & 255;
    int b = rem >> 5, c = rem & 31;
    int dil = i + 1;
    const float* xin = x + ((size_t)(b*128 + i*32 + c))*4096;
    float wkw[7], wkh[7], wk3[9];
    #pragma unroll
    for(int t=0;t<7;t++){ wkw[t]=P.kw[i][c*7+t]; wkh[t]=P.kh[i][c*7+t]; }
    #pragma unroll
    for(int t=0;t<9;t++) wk3[t]=P.k3[i][c*9+t];
    float gc = P.g[i][c], bc = P.b[i][c];
    int tid = threadIdx.x;
    for(int idx=tid; idx<4096; idx+=256) s0[idx]=xin[idx];
    __syncthreads();
    for(int idx=tid; idx<4096; idx+=256){
        int h=idx>>6, w=idx&63; float a=0.f;
        #pragma unroll
        for(int t=0;t<7;t++){ int ww=w+(t-3)*dil; if(ww>=0&&ww<64) a=fmaf(s0[h*64+ww],wkw[t],a); }
        s1[idx]=a;
    }
    __syncthreads();
    for(int idx=tid; idx<4096; idx+=256){
        int h=idx>>6, w=idx&63; float a=0.f;
        #pragma unroll
        for(int t=0;t<7;t++){ int hh=h+(t-3)*dil; if(hh>=0&&hh<64) a=fmaf(s1[hh*64+w],wkh[t],a); }
        s0[idx]=a;
    }
    __syncthreads();
    const float inv = rsqrtf(1.00001f);
    float* out = Y0 + ((size_t)(i*8+b)*32 + c)*4096;
    for(int idx=tid; idx<4096; idx+=256){
        int h=idx>>6, w=idx&63; float a=0.f;
        #pragma unroll
        for(int t=0;t<9;t++){
            int hh=h+((t/3)-1)*dil, ww=w+((t%3)-1)*dil;
            if(hh>=0&&hh<64&&ww>=0&&ww<64) a=fmaf(s0[hh*64+ww],wk3[t],a);
        }
        out[idx] = a*inv*gc + bc + xin[idx];
    }
}

// ---- K2: channel LayerNorm(32) + in_proj (32->128) -> XW (bf16), ZS = silu(z) (bf16) ----
__global__ __launch_bounds__(256) void k_lnproj(const float* __restrict__ Y0,
        const float* __restrict__ ln_g, const float* __restrict__ ln_b,
        const float* __restrict__ in_w, ushort_t* __restrict__ XW, ushort_t* __restrict__ ZS){
    __shared__ float W[128*32];
    int tid=threadIdx.x;
    for(int idx=tid; idx<4096; idx+=256) W[idx]=in_w[idx];
    __syncthreads();
    int pg = blockIdx.x*256 + tid;
    int ib = pg>>12, p = pg&4095;
    const float* src = Y0 + (size_t)ib*32*4096;
    float t[32];
    float mu=0.f;
    #pragma unroll
    for(int c=0;c<32;c++){ t[c]=src[c*4096+p]; mu+=t[c]; }
    mu *= (1.f/32.f);
    float v=0.f;
    #pragma unroll
    for(int c=0;c<32;c++){ float d=t[c]-mu; v+=d*d; }
    v *= (1.f/32.f);
    float rs = rsqrtf(v+1e-5f);
    #pragma unroll
    for(int c=0;c<32;c++) t[c] = (t[c]-mu)*rs*ln_g[c] + ln_b[c];
    ushort_t* xw = XW + (size_t)ib*64*4096 + p;
    ushort_t* zs = ZS + (size_t)ib*64*4096 + p;
    for(int j=0;j<64;j++){
        float a=0.f, a2=0.f;
        #pragma unroll
        for(int c=0;c<32;c++){
            a  = fmaf(t[c], W[j*32+c],      a);
            a2 = fmaf(t[c], W[(j+64)*32+c], a2);
        }
        xw[(size_t)j*4096] = f2b(a);
        zs[(size_t)j*4096] = f2b(siluf(a2));
    }
}

// ---- K3: depthwise 3x3 + bias + silu -> XC (bf16 in/out) ----
__global__ __launch_bounds__(256) void k_dwsilu(const ushort_t* __restrict__ XW,
        const float* __restrict__ cw, const float* __restrict__ cb, ushort_t* __restrict__ XC){
    int g = blockIdx.x*256+threadIdx.x;
    int pd = g>>12; int p=g&4095; int d = pd&63;
    int h=p>>6, w=p&63;
    const ushort_t* src = XW + (size_t)pd*4096;
    float a = cb[d];
    #pragma unroll
    for(int t=0;t<9;t++){
        int hh=h+(t/3)-1, ww=w+(t%3)-1;
        if(hh>=0&&hh<64&&ww>=0&&ww<64) a=fmaf(b2f(src[hh*64+ww]),cw[d*9+t],a);
    }
    XC[g]=f2b(siluf(a));
}

// ---- transpose 64x64 bf16 planes ----
__global__ __launch_bounds__(256) void k_transpose(const ushort_t* __restrict__ src, ushort_t* __restrict__ dst){
    __shared__ ushort_t tile[64*66];
    size_t plane = blockIdx.x;
    const ushort_t* s = src + plane*4096;
    ushort_t* d = dst + plane*4096;
    int tid=threadIdx.x;
    for(int idx=tid; idx<4096; idx+=256){
        int h=idx>>6, w=idx&63;
        tile[w*66+h]=s[idx];
    }
    __syncthreads();
    for(int idx=tid; idx<4096; idx+=256){
        d[idx]=tile[(idx>>6)*66 + (idx&63)];
    }
}

// ---- K4: x_dbl rows: delta rows (2) -> DT f32; B/C rows (32) -> XB bf16; scan order ----
__global__ __launch_bounds__(256) void k_xdbl(const ushort_t* __restrict__ XC, const ushort_t* __restrict__ XCT,
        const float* __restrict__ xproj, ushort_t* __restrict__ XB, float* __restrict__ DT){
    __shared__ float W[34*64];
    int bid=blockIdx.x; int tid=threadIdx.x;
    int ibk = bid>>4; int lb = bid&15;
    int k = ibk & 3; int ib = ibk>>2;
    for(int idx=tid; idx<2176; idx+=256) W[idx]=xproj[k*2176+idx];
    __syncthreads();
    int l = lb*256+tid;                          // scan index
    const ushort_t* src = ((k&1)?XCT:XC) + (size_t)ib*64*4096;
    int idxl = (k&2)? (4095-l) : l;
    float acc[34];
    #pragma unroll
    for(int c=0;c<34;c++) acc[c]=0.f;
    for(int dd=0;dd<64;dd++){
        float u = b2f(src[(size_t)dd*4096 + idxl]);
        #pragma unroll
        for(int c=0;c<34;c++) acc[c] = fmaf(u, W[c*64+dd], acc[c]);
    }
    DT[((size_t)ibk*2)*4096 + l]   = acc[0];
    DT[((size_t)ibk*2+1)*4096 + l] = acc[1];
    ushort_t* o = XB + ((size_t)ibk*32)*4096 + l;
    #pragma unroll
    for(int c=0;c<32;c++) o[(size_t)c*4096]=f2b(acc[2+c]);
}

// ---- K5: scan phase 1 — per-chunk local states + delta sums. block = (ib, p, ch);
//      wave0 = forward dir k=p (scan ascending), wave1 = backward dir k=p+2 ----
__global__ __launch_bounds__(128) void k_scan1(const ushort_t* __restrict__ XB, const float* __restrict__ DT,
        const ushort_t* __restrict__ XC, const ushort_t* __restrict__ XCT,
        const float* __restrict__ dtw, const float* __restrict__ dtb,
        const float* __restrict__ A_logs,
        ushort_t* __restrict__ CHS, float* __restrict__ SD){
    __shared__ float sx[2*32*64];
    __shared__ float sdt[2*2*64];
    __shared__ ushort_t su[64*66];
    int bid=blockIdx.x, tid=threadIdx.x;
    int ib = bid>>7; int rem = bid&127; int p = rem>>6; int ch = rem&63;
    int w = tid>>6, d = tid&63;
    int l0 = ch*64;
    const ushort_t* X0 = XB + ((size_t)(4*ib+p)*32)*4096;
    const ushort_t* X2 = XB + ((size_t)(4*ib+p+2)*32)*4096;
    for(int idx=tid; idx<2048; idx+=128){
        int c=idx>>6, jj=idx&63;
        sx[idx] = b2f(X0[(size_t)c*4096 + l0 + jj]);
        sx[2048 + c*64 + (63-jj)] = b2f(X2[(size_t)c*4096 + 4032 - l0 + jj]);
    }
    {
        const float* D0 = DT + ((size_t)(4*ib+p)*2)*4096;
        const float* D2 = DT + ((size_t)(4*ib+p+2)*2)*4096;
        int c=tid>>6, jj=tid&63;
        sdt[tid] = D0[(size_t)c*4096 + l0 + jj];
        sdt[128 + c*64 + (63-jj)] = D2[(size_t)c*4096 + 4032 - l0 + jj];
    }
    const ushort_t* U = (p?XCT:XC) + (size_t)ib*64*4096;
    for(int idx=tid; idx<4096; idx+=128){
        int r=idx>>6, jj=idx&63;
        su[r*66+jj] = U[(size_t)r*4096 + l0 + jj];
    }
    __syncthreads();
    int k = p + 2*w;
    float dt0=dtw[(k*64+d)*2], dt1=dtw[(k*64+d)*2+1], db=dtb[k*64+d];
    float An[16];
    #pragma unroll
    for(int n=0;n<16;n++) An[n] = -__expf(A_logs[(k*64+d)*16+n]);
    const float* sxw = sx + w*2048;
    const float* sdw = sdt + w*128;
    float h[16];
    #pragma unroll
    for(int n=0;n<16;n++) h[n]=0.f;
    float S=0.f;
    for(int jj=0;jj<64;jj++){
        int j = w ? (63-jj) : jj;
        float delta = softplusf(fmaf(dt0,sdw[j],fmaf(dt1,sdw[64+j],db)));
        S += delta;
        float u = b2f(su[d*66+j]);
        float du = delta*u;
        #pragma unroll
        for(int n=0;n<16;n++){
            float a = __expf(delta*An[n]);
            h[n] = fmaf(h[n], a, du*sxw[n*64+j]);
        }
    }
    int chd = w ? (63-ch) : ch;
    size_t o = ((size_t)(4*ib+k)*64 + chd)*1024 + d*16;
    #pragma unroll
    for(int n=0;n<16;n++) CHS[o+n]=f2b(h[n]);
    SD[((size_t)(4*ib+k)*64 + chd)*64 + d]=S;
}

// ---- K5b: chunk-level exclusive scan (64 chunks, scan order) ----
__global__ __launch_bounds__(1024) void k_scan2(const float* __restrict__ A_logs,
        const float* __restrict__ SD, ushort_t* __restrict__ CHS){
    int ibk=blockIdx.x; int tid=threadIdx.x;
    int d=tid>>4, n=tid&15, k=ibk&3;
    float An = -__expf(A_logs[(k*64+d)*16+n]);
    float H=0.f;
    for(int c=0;c<64;c++){
        float s = SD[((size_t)ibk*64+c)*64 + d];
        float pc = __expf(An*s);
        size_t o = ((size_t)ibk*64+c)*1024 + tid;
        float loc = b2f(CHS[o]);
        CHS[o]=f2b(H);
        H = fmaf(H, pc, loc);
    }
}

// ---- K6: scan phase 3 — re-run chunks from entry states, merge fwd+bwd y in LDS ----
__global__ __launch_bounds__(128) void k_scan3(const ushort_t* __restrict__ XB, const float* __restrict__ DT,
        const ushort_t* __restrict__ XC, const ushort_t* __restrict__ XCT,
        const float* __restrict__ dtw, const float* __restrict__ dtb,
        const float* __restrict__ A_logs, const float* __restrict__ Ds,
        const ushort_t* __restrict__ CHS,
        ushort_t* __restrict__ Y1, ushort_t* __restrict__ Y2){
    __shared__ float sx[2*32*64];
    __shared__ float sdt[2*2*64];
    __shared__ ushort_t su[64*66];
    __shared__ float sy_lo[64*33];
    __shared__ float sy_hi[64*33];
    int bid=blockIdx.x, tid=threadIdx.x;
    int ib = bid>>7; int rem = bid&127; int p = rem>>6; int ch = rem&63;
    int w = tid>>6, d = tid&63;
    int l0 = ch*64;
    const ushort_t* X0 = XB + ((size_t)(4*ib+p)*32)*4096;
    const ushort_t* X2 = XB + ((size_t)(4*ib+p+2)*32)*4096;
    for(int idx=tid; idx<2048; idx+=128){
        int c=idx>>6, jj=idx&63;
        sx[idx] = b2f(X0[(size_t)c*4096 + l0 + jj]);
        sx[2048 + c*64 + (63-jj)] = b2f(X2[(size_t)c*4096 + 4032 - l0 + jj]);
    }
    {
        const float* D0 = DT + ((size_t)(4*ib+p)*2)*4096;
        const float* D2 = DT + ((size_t)(4*ib+p+2)*2)*4096;
        int c=tid>>6, jj=tid&63;
        sdt[tid] = D0[(size_t)c*4096 + l0 + jj];
        sdt[128 + c*64 + (63-jj)] = D2[(size_t)c*4096 + 4032 - l0 + jj];
    }
    const ushort_t* U = (p?XCT:XC) + (size_t)ib*64*4096;
    for(int idx=tid; idx<4096; idx+=128){
        int r=idx>>6, jj=idx&63;
        su[r*66+jj] = U[(size_t)r*4096 + l0 + jj];
    }
    __syncthreads();
    int k = p + 2*w;
    float dt0=dtw[(k*64+d)*2], dt1=dtw[(k*64+d)*2+1], db=dtb[k*64+d];
    float An[16];
    #pragma unroll
    for(int n=0;n<16;n++) An[n] = -__expf(A_logs[(k*64+d)*16+n]);
    const float* sxw = sx + w*2048;
    const float* sdw = sdt + w*128;
    int chd = w ? (63-ch) : ch;
    const ushort_t* e = CHS + ((size_t)(4*ib+k)*64 + chd)*1024 + d*16;
    float h[16];
    #pragma unroll
    for(int n=0;n<16;n++) h[n]=b2f(e[n]);
    float Dkd = Ds[k*64+d];
    for(int seg=0; seg<2; ++seg){
        for(int t=0; t<32; ++t){
            int jj = seg*32 + t;
            int j = w ? (63-jj) : jj;
            float delta = softplusf(fmaf(dt0,sdw[j],fmaf(dt1,sdw[64+j],db)));
            float u = b2f(su[d*66+j]);
            float du = delta*u;
            float y=0.f;
            #pragma unroll
            for(int n=0;n<16;n++){
                float a = __expf(delta*An[n]);
                h[n] = fmaf(h[n], a, du*sxw[n*64+j]);
                y = fmaf(h[n], sxw[(16+n)*64+j], y);
            }
            y = fmaf(Dkd, u, y);
            if(seg==0){
                if(j<32) sy_lo[d*33+j]=y; else sy_hi[d*33+j-32]=y;
            } else {
                if(j<32) sy_lo[d*33+j]+=y; else sy_hi[d*33+j-32]+=y;
            }
        }
        __syncthreads();
    }
    ushort_t* Yb = (p?Y2:Y1) + (size_t)ib*64*4096;
    for(int idx=tid; idx<4096; idx+=128){
        int r=idx>>6, j=idx&63;
        float v = (j<32)? sy_lo[r*33+j] : sy_hi[r*33+j-32];
        Yb[(size_t)r*4096 + l0 + j] = f2b(v);
    }
}

// ---- K8: out-LN(64) + gate + out-proj (64->32) + residual + scale + BN + ReLU (f32 out) ----
__global__ __launch_bounds__(256) void k_final(const ushort_t* __restrict__ Y1, const ushort_t* __restrict__ Y2T,
        const ushort_t* __restrict__ ZS, const float* __restrict__ Y0,
        const float* __restrict__ on_g, const float* __restrict__ on_b,
        const float* __restrict__ out_w,
        const float* __restrict__ s1, const float* __restrict__ s2, const float* __restrict__ s3,
        const float* __restrict__ bn_g, const float* __restrict__ bn_b,
        float* __restrict__ out){
    __shared__ float W[32*64];
    int tid=threadIdx.x;
    for(int idx=tid; idx<2048; idx+=256) W[idx]=out_w[idx];
    __syncthreads();
    int pg=blockIdx.x*256+tid;
    int ib=pg>>12, p=pg&4095;
    int i=ib>>3, b=ib&7;
    float y[64];
    const ushort_t* y1 = Y1 + (size_t)ib*64*4096 + p;
    const ushort_t* y2 = Y2T + (size_t)ib*64*4096 + p;
    float mu=0.f;
    #pragma unroll
    for(int dd=0;dd<64;dd++){ y[dd]=b2f(y1[(size_t)dd*4096])+b2f(y2[(size_t)dd*4096]); mu+=y[dd]; }
    mu*=(1.f/64.f);
    float v=0.f;
    #pragma unroll
    for(int dd=0;dd<64;dd++){ float q=y[dd]-mu; v+=q*q; }
    v*=(1.f/64.f);
    float rs=rsqrtf(v+1e-5f);
    const ushort_t* zs = ZS + (size_t)ib*64*4096 + p;
    #pragma unroll
    for(int dd=0;dd<64;dd++){
        float yn=(y[dd]-mu)*rs*on_g[dd]+on_b[dd];
        y[dd]=yn*b2f(zs[(size_t)dd*4096]);
    }
    float sc = (i==0)?s1[0]:((i==1)?s2[0]:s3[0]);
    const float inv = rsqrtf(1.00001f);
    const float* y0 = Y0 + (size_t)ib*32*4096 + p;
    for(int c=0;c<32;c++){
        float a=0.f;
        #pragma unroll
        for(int dd=0;dd<64;dd++) a=fmaf(y[dd],W[c*64+dd],a);
        float o=(y0[(size_t)c*4096]+a)*sc;
        int chn=i*32+c;
        float vv=fmaf(o*inv, bn_g[chn], bn_b[chn]);
        out[((size_t)b*128+chn)*4096 + p]=fmaxf(vv,0.f);
    }
}

// ---- K9: branch 4 passthrough * scale4 + BN + ReLU (f32 out) ----
__global__ __launch_bounds__(256) void k_branch4(const float* __restrict__ x,
        const float* __restrict__ s4, const float* __restrict__ bn_g,
        const float* __restrict__ bn_b, float* __restrict__ out){
    int g=blockIdx.x*256+threadIdx.x;
    int b=g>>17; int rem=g&131071; int c=rem>>12; int p=rem&4095;
    int chn=96+c;
    const float inv=rsqrtf(1.00001f);
    float v=x[((size_t)b*128+chn)*4096+p]*s4[0];
    v=fmaf(v*inv, bn_g[chn], bn_b[chn]);
    out[((size_t)b*128+chn)*4096+p]=fmaxf(v,0.f);
}

extern "C" void kernel_launch(void* const* d_in, const int* in_sizes, int n_in,
                              void* d_out, int out_size, void* d_ws, size_t ws_size,
                              hipStream_t stream) {
    const float* x      = (const float*)d_in[0];
    const float* ln_g   = (const float*)d_in[16];
    const float* ln_b   = (const float*)d_in[17];
    const float* in_w   = (const float*)d_in[18];
    const float* conv_w = (const float*)d_in[19];
    const float* conv_b = (const float*)d_in[20];
    const float* xproj  = (const float*)d_in[21];
    const float* dtw    = (const float*)d_in[22];
    const float* dtb    = (const float*)d_in[23];
    const float* A_logs = (const float*)d_in[24];
    const float* Ds     = (const float*)d_in[25];
    const float* on_g   = (const float*)d_in[26];
    const float* on_b   = (const float*)d_in[27];
    const float* out_w  = (const float*)d_in[28];
    const float* sc1    = (const float*)d_in[29];
    const float* sc2    = (const float*)d_in[30];
    const float* sc3    = (const float*)d_in[31];
    const float* sc4    = (const float*)d_in[32];
    const float* bn_g   = (const float*)d_in[33];
    const float* bn_b   = (const float*)d_in[34];

    AxialParams P;
    for(int i=0;i<3;i++){
        P.kh[i]=(const float*)d_in[1+5*i];
        P.kw[i]=(const float*)d_in[2+5*i];
        P.k3[i]=(const float*)d_in[3+5*i];
        P.g[i] =(const float*)d_in[4+5*i];
        P.b[i] =(const float*)d_in[5+5*i];
    }

    // ---- workspace layout (bytes); total ~118 MB ----
    char* base = (char*)d_ws;
    float*    Y0   = (float*)   (base + 0);            // 12,582,912 f32
    ushort_t* ZS   = (ushort_t*)(base + 12582912);     // 12,582,912 bf16
    ushort_t* XC   = (ushort_t*)(base + 25165824);     // 12,582,912 bf16; later Y2T
    ushort_t* XCT  = (ushort_t*)(base + 37748736);     // 12,582,912 bf16
    ushort_t* XB   = (ushort_t*)(base + 50331648);     // 25,165,824 bf16 (32 B/C rows)
    ushort_t* XW   = (ushort_t*)(base + 50331648);     // alias (dead before k_xdbl writes)
    float*    DT   = (float*)   (base + 75497472);     //  3,145,728 f32 (2 delta rows)
    ushort_t* CHS  = (ushort_t*)(base + 78643200);     // 12,582,912 bf16
    float*    SD   = (float*)   (base + 91226112);     //  1,572,864 f32
    ushort_t* Y1   = (ushort_t*)(base + 92798976);     // 12,582,912 bf16
    ushort_t* Y2   = (ushort_t*)(base + 105381888);    // 12,582,912 bf16  (end 117,964,800)
    ushort_t* Y2T  = XC;                               // alias (XC dead after scan3)

    float* out = (float*)d_out;

    k_axial    <<<768,   256, 0, stream>>>(x, Y0, P);
    k_lnproj   <<<384,   256, 0, stream>>>(Y0, ln_g, ln_b, in_w, XW, ZS);
    k_dwsilu   <<<24576, 256, 0, stream>>>(XW, conv_w, conv_b, XC);
    k_transpose<<<1536,  256, 0, stream>>>(XC, XCT);
    k_xdbl     <<<1536,  256, 0, stream>>>(XC, XCT, xproj, XB, DT);
    k_scan1    <<<3072,  128, 0, stream>>>(XB, DT, XC, XCT, dtw, dtb, A_logs, CHS, SD);
    k_scan2    <<<96,   1024, 0, stream>>>(A_logs, SD, CHS);
    k_scan3    <<<3072,  128, 0, stream>>>(XB, DT, XC, XCT, dtw, dtb, A_logs, Ds, CHS, Y1, Y2);
    k_transpose<<<1536,  256, 0, stream>>>(Y2, Y2T);
    k_final    <<<384,   256, 0, stream>>>(Y1, Y2T, ZS, Y0, on_g, on_b, out_w,
                                           sc1, sc2, sc3, bn_g, bn_b, out);
    k_branch4  <<<4096,  256, 0, stream>>>(x, sc4, bn_g, bn_b, out);
}

// Round 4
// 469.597 us; speedup vs baseline: 1.3409x; 1.3409x over previous
//
#include <hip/hip_runtime.h>
#include <hip/hip_bf16.h>
#include <cstdint>

typedef unsigned short ushort_t;

__device__ __forceinline__ float softplusf(float x){
    return fmaxf(x, 0.f) + log1pf(__expf(-fabsf(x)));
}
__device__ __forceinline__ float siluf(float x){
    return x / (1.f + __expf(-x));
}
__device__ __forceinline__ float b2f(ushort_t u){
    union { uint32_t i; float f; } v; v.i = ((uint32_t)u)<<16; return v.f;
}
__device__ __forceinline__ ushort_t f2b(float f){
    uint32_t x = __float_as_uint(f);
    uint32_t r = (x + 0x7FFFu + ((x>>16)&1u)) >> 16;
    return (ushort_t)r;
}

struct AxialParams {
    const float* kh[3]; const float* kw[3]; const float* k3[3];
    const float* g[3];  const float* b[3];
};

// ---- K1: axial depthwise chain (kw -> kh -> 3x3) + BN + residual (f32 in, f32 out) ----
__global__ __launch_bounds__(256) void k_axial(const float* __restrict__ x,
                                               float* __restrict__ Y0, AxialParams P){
    __shared__ float s0[4096];
    __shared__ float s1[4096];
    int bid = blockIdx.x;
    int i = bid >> 8;            // branch
    int rem = bid & 255;
    int b = rem >> 5, c = rem & 31;
    int dil = i + 1;
    const float* xin = x + ((size_t)(b*128 + i*32 + c))*4096;
    float wkw[7], wkh[7], wk3[9];
    #pragma unroll
    for(int t=0;t<7;t++){ wkw[t]=P.kw[i][c*7+t]; wkh[t]=P.kh[i][c*7+t]; }
    #pragma unroll
    for(int t=0;t<9;t++) wk3[t]=P.k3[i][c*9+t];
    float gc = P.g[i][c], bc = P.b[i][c];
    int tid = threadIdx.x;
    for(int idx=tid; idx<4096; idx+=256) s0[idx]=xin[idx];
    __syncthreads();
    for(int idx=tid; idx<4096; idx+=256){
        int h=idx>>6, w=idx&63; float a=0.f;
        #pragma unroll
        for(int t=0;t<7;t++){ int ww=w+(t-3)*dil; if(ww>=0&&ww<64) a=fmaf(s0[h*64+ww],wkw[t],a); }
        s1[idx]=a;
    }
    __syncthreads();
    for(int idx=tid; idx<4096; idx+=256){
        int h=idx>>6, w=idx&63; float a=0.f;
        #pragma unroll
        for(int t=0;t<7;t++){ int hh=h+(t-3)*dil; if(hh>=0&&hh<64) a=fmaf(s1[hh*64+w],wkh[t],a); }
        s0[idx]=a;
    }
    __syncthreads();
    const float inv = rsqrtf(1.00001f);
    float* out = Y0 + ((size_t)(i*8+b)*32 + c)*4096;
    for(int idx=tid; idx<4096; idx+=256){
        int h=idx>>6, w=idx&63; float a=0.f;
        #pragma unroll
        for(int t=0;t<9;t++){
            int hh=h+((t/3)-1)*dil, ww=w+((t%3)-1)*dil;
            if(hh>=0&&hh<64&&ww>=0&&ww<64) a=fmaf(s0[hh*64+ww],wk3[t],a);
        }
        out[idx] = a*inv*gc + bc + xin[idx];
    }
}

// ---- K2: channel LayerNorm(32) + in_proj (32->128) -> XW (bf16), ZS = silu(z) (bf16) ----
__global__ __launch_bounds__(256) void k_lnproj(const float* __restrict__ Y0,
        const float* __restrict__ ln_g, const float* __restrict__ ln_b,
        const float* __restrict__ in_w, ushort_t* __restrict__ XW, ushort_t* __restrict__ ZS){
    __shared__ float W[128*32];
    int tid=threadIdx.x;
    for(int idx=tid; idx<4096; idx+=256) W[idx]=in_w[idx];
    __syncthreads();
    int pg = blockIdx.x*256 + tid;
    int ib = pg>>12, p = pg&4095;
    const float* src = Y0 + (size_t)ib*32*4096;
    float t[32];
    float mu=0.f;
    #pragma unroll
    for(int c=0;c<32;c++){ t[c]=src[c*4096+p]; mu+=t[c]; }
    mu *= (1.f/32.f);
    float v=0.f;
    #pragma unroll
    for(int c=0;c<32;c++){ float d=t[c]-mu; v+=d*d; }
    v *= (1.f/32.f);
    float rs = rsqrtf(v+1e-5f);
    #pragma unroll
    for(int c=0;c<32;c++) t[c] = (t[c]-mu)*rs*ln_g[c] + ln_b[c];
    ushort_t* xw = XW + (size_t)ib*64*4096 + p;
    ushort_t* zs = ZS + (size_t)ib*64*4096 + p;
    for(int j=0;j<64;j++){
        float a=0.f, a2=0.f;
        #pragma unroll
        for(int c=0;c<32;c++){
            a  = fmaf(t[c], W[j*32+c],      a);
            a2 = fmaf(t[c], W[(j+64)*32+c], a2);
        }
        xw[(size_t)j*4096] = f2b(a);
        zs[(size_t)j*4096] = f2b(siluf(a2));
    }
}

// ---- K3: depthwise 3x3 + bias + silu -> XC (bf16 in/out) ----
__global__ __launch_bounds__(256) void k_dwsilu(const ushort_t* __restrict__ XW,
        const float* __restrict__ cw, const float* __restrict__ cb, ushort_t* __restrict__ XC){
    int g = blockIdx.x*256+threadIdx.x;
    int pd = g>>12; int p=g&4095; int d = pd&63;
    int h=p>>6, w=p&63;
    const ushort_t* src = XW + (size_t)pd*4096;
    float a = cb[d];
    #pragma unroll
    for(int t=0;t<9;t++){
        int hh=h+(t/3)-1, ww=w+(t%3)-1;
        if(hh>=0&&hh<64&&ww>=0&&ww<64) a=fmaf(b2f(src[hh*64+ww]),cw[d*9+t],a);
    }
    XC[g]=f2b(siluf(a));
}

// ---- transpose 64x64 bf16 planes ----
__global__ __launch_bounds__(256) void k_transpose(const ushort_t* __restrict__ src, ushort_t* __restrict__ dst){
    __shared__ ushort_t tile[64*66];
    size_t plane = blockIdx.x;
    const ushort_t* s = src + plane*4096;
    ushort_t* d = dst + plane*4096;
    int tid=threadIdx.x;
    for(int idx=tid; idx<4096; idx+=256){
        int h=idx>>6, w=idx&63;
        tile[w*66+h]=s[idx];
    }
    __syncthreads();
    for(int idx=tid; idx<4096; idx+=256){
        d[idx]=tile[(idx>>6)*66 + (idx&63)];
    }
}

// ---- K4: x_dbl rows: delta rows (2) -> DT f32; B rows -> XBb bf16; C rows -> XCc bf16 ----
__global__ __launch_bounds__(256) void k_xdbl(const ushort_t* __restrict__ XC, const ushort_t* __restrict__ XCT,
        const float* __restrict__ xproj, ushort_t* __restrict__ XBb, ushort_t* __restrict__ XCc,
        float* __restrict__ DT){
    __shared__ float Wt[64][36];
    int bid=blockIdx.x; int tid=threadIdx.x;
    int ibk = bid>>4; int lb = bid&15;
    int k = ibk & 3; int ib = ibk>>2;
    for(int idx=tid; idx<2176; idx+=256){
        int c=idx>>6, dd=idx&63;
        Wt[dd][c]=xproj[k*2176+idx];
    }
    __syncthreads();
    int l = lb*256+tid;                          // scan index
    const ushort_t* src = ((k&1)?XCT:XC) + (size_t)ib*64*4096;
    int idxl = (k&2)? (4095-l) : l;
    float acc[34];
    #pragma unroll
    for(int c=0;c<34;c++) acc[c]=0.f;
    for(int dd=0;dd<64;dd++){
        float u = b2f(src[(size_t)dd*4096 + idxl]);
        float wv[36];
        const float4* wp = reinterpret_cast<const float4*>(&Wt[dd][0]);
        *reinterpret_cast<float4*>(&wv[0])  = wp[0];
        *reinterpret_cast<float4*>(&wv[4])  = wp[1];
        *reinterpret_cast<float4*>(&wv[8])  = wp[2];
        *reinterpret_cast<float4*>(&wv[12]) = wp[3];
        *reinterpret_cast<float4*>(&wv[16]) = wp[4];
        *reinterpret_cast<float4*>(&wv[20]) = wp[5];
        *reinterpret_cast<float4*>(&wv[24]) = wp[6];
        *reinterpret_cast<float4*>(&wv[28]) = wp[7];
        *reinterpret_cast<float2*>(&wv[32]) = *reinterpret_cast<const float2*>(&Wt[dd][32]);
        #pragma unroll
        for(int c=0;c<34;c++) acc[c] = fmaf(u, wv[c], acc[c]);
    }
    DT[((size_t)ibk*2)*4096 + l]   = acc[0];
    DT[((size_t)ibk*2+1)*4096 + l] = acc[1];
    ushort_t* ob = XBb + ((size_t)ibk*16)*4096 + l;
    ushort_t* oc = XCc + ((size_t)ibk*16)*4096 + l;
    #pragma unroll
    for(int c=0;c<16;c++){
        ob[(size_t)c*4096]=f2b(acc[2+c]);
        oc[(size_t)c*4096]=f2b(acc[18+c]);
    }
}

// ---- K5: scan phase 1 — per-chunk local states + delta sums ----
// block=(ib,p,ch); wave0 = dir k=p (fwd), wave1 = dir k=p+2 (bwd, same spatial tile)
__global__ __launch_bounds__(128) void k_scan1(const ushort_t* __restrict__ XBb, const float* __restrict__ DT,
        const ushort_t* __restrict__ XC, const ushort_t* __restrict__ XCT,
        const float* __restrict__ dtw, const float* __restrict__ dtb,
        const float* __restrict__ A_logs,
        ushort_t* __restrict__ CHS, float* __restrict__ SD){
    __shared__ float sB[2][64][16];
    __shared__ float sdt[2][64][2];
    __shared__ ushort_t su[64*68];
    int bid=blockIdx.x, tid=threadIdx.x;
    int ib = bid>>7; int rem = bid&127; int p = rem>>6; int ch = rem&63;
    int w = tid>>6, d = tid&63;
    int l0 = ch*64;
    int r0 = 4032 - l0;   // bwd dir scan-range base
    const ushort_t* B0 = XBb + (size_t)(4*ib+p)*16*4096;
    const ushort_t* B1 = XBb + (size_t)(4*ib+p+2)*16*4096;
    for(int idx=tid; idx<256; idx+=128){
        int n=idx>>4, q=(idx&15)*4;
        ushort4 v0 = *reinterpret_cast<const ushort4*>(&B0[(size_t)n*4096 + l0 + q]);
        ushort4 v1 = *reinterpret_cast<const ushort4*>(&B1[(size_t)n*4096 + r0 + q]);
        sB[0][q+0][n]=b2f(v0.x); sB[0][q+1][n]=b2f(v0.y); sB[0][q+2][n]=b2f(v0.z); sB[0][q+3][n]=b2f(v0.w);
        sB[1][q+0][n]=b2f(v1.x); sB[1][q+1][n]=b2f(v1.y); sB[1][q+2][n]=b2f(v1.z); sB[1][q+3][n]=b2f(v1.w);
    }
    {
        const float* D0 = DT + (size_t)(4*ib+p)*2*4096;
        const float* D1 = DT + (size_t)(4*ib+p+2)*2*4096;
        int r=tid>>6, s=tid&63;
        sdt[0][s][r] = D0[(size_t)r*4096 + l0 + s];
        sdt[1][s][r] = D1[(size_t)r*4096 + r0 + s];
    }
    const ushort_t* U = (p?XCT:XC) + (size_t)ib*64*4096;
    for(int idx=tid; idx<1024; idx+=128){
        int rr=idx>>4, q=(idx&15)*4;
        *reinterpret_cast<ushort4*>(&su[rr*68+q]) =
            *reinterpret_cast<const ushort4*>(&U[(size_t)rr*4096 + l0 + q]);
    }
    __syncthreads();
    int k = p + 2*w;
    float dt0=dtw[(k*64+d)*2], dt1=dtw[(k*64+d)*2+1], db=dtb[k*64+d];
    float An[16];
    #pragma unroll
    for(int n=0;n<16;n++) An[n] = -__expf(A_logs[(k*64+d)*16+n]);
    float An0 = An[0];
    bool st = true;
    #pragma unroll
    for(int n=1;n<16;n++) st = st && (fabsf(An[n]-(n+1)*An0) <= 1e-4f*fabsf(An[n]) + 1e-6f);
    bool uni = (bool)__all((int)st);
    float h[16];
    #pragma unroll
    for(int n=0;n<16;n++) h[n]=0.f;
    float S=0.f;

#define SCAN1_COMMON \
        float2 dtv = *reinterpret_cast<const float2*>(&sdt[w][s][0]); \
        float delta = softplusf(fmaf(dt0, dtv.x, fmaf(dt1, dtv.y, db))); \
        S += delta; \
        int j = w ? 63 - s : s; \
        float du = delta * b2f(su[d*68 + j]); \
        float bb[16]; \
        { const float4* bp = reinterpret_cast<const float4*>(&sB[w][s][0]); \
          *reinterpret_cast<float4*>(&bb[0])  = bp[0]; \
          *reinterpret_cast<float4*>(&bb[4])  = bp[1]; \
          *reinterpret_cast<float4*>(&bb[8])  = bp[2]; \
          *reinterpret_cast<float4*>(&bb[12]) = bp[3]; }

    if(uni){
        for(int s=0;s<64;s++){
            SCAN1_COMMON
            float rr = __expf(delta*An0); float a = rr;
            #pragma unroll
            for(int n=0;n<16;n++){ h[n] = fmaf(h[n], a, du*bb[n]); a *= rr; }
        }
    } else {
        for(int s=0;s<64;s++){
            SCAN1_COMMON
            #pragma unroll
            for(int n=0;n<16;n++){ float a = __expf(delta*An[n]); h[n] = fmaf(h[n], a, du*bb[n]); }
        }
    }
#undef SCAN1_COMMON
    int chd = w ? 63-ch : ch;
    ushort_t* o = CHS + ((size_t)(4*ib+k)*64 + chd)*1024 + d*16;
    #pragma unroll
    for(int n=0;n<16;n++) o[n]=f2b(h[n]);
    SD[((size_t)(4*ib+k)*64 + chd)*64 + d]=S;
}

// ---- K5b: chunk-level exclusive scan (64 chunks, scan order) ----
__global__ __launch_bounds__(1024) void k_scan2(const float* __restrict__ A_logs,
        const float* __restrict__ SD, ushort_t* __restrict__ CHS){
    int ibk=blockIdx.x; int tid=threadIdx.x;
    int d=tid>>4, n=tid&15, k=ibk&3;
    float An = -__expf(A_logs[(k*64+d)*16+n]);
    float H=0.f;
    for(int c=0;c<64;c++){
        float s = SD[((size_t)ibk*64+c)*64 + d];
        float pc = __expf(An*s);
        size_t o = ((size_t)ibk*64+c)*1024 + tid;
        float loc = b2f(CHS[o]);
        CHS[o]=f2b(H);
        H = fmaf(H, pc, loc);
    }
}

// ---- K6: scan phase 3 — re-run chunks from entry states, merge fwd+bwd y in LDS ----
__global__ __launch_bounds__(128) void k_scan3(const ushort_t* __restrict__ XBb, const ushort_t* __restrict__ XCc,
        const float* __restrict__ DT,
        const ushort_t* __restrict__ XC, const ushort_t* __restrict__ XCT,
        const float* __restrict__ dtw, const float* __restrict__ dtb,
        const float* __restrict__ A_logs,
        const ushort_t* __restrict__ CHS,
        ushort_t* __restrict__ Y1, ushort_t* __restrict__ Y2){
    __shared__ float sB[2][64][16];
    __shared__ float sC[2][64][16];
    __shared__ float sdt[2][64][2];
    __shared__ ushort_t su[64*68];
    __shared__ ushort_t sy[64*68];
    int bid=blockIdx.x, tid=threadIdx.x;
    int ib = bid>>7; int rem = bid&127; int p = rem>>6; int ch = rem&63;
    int w = tid>>6, d = tid&63;
    int l0 = ch*64;
    int r0 = 4032 - l0;
    const ushort_t* B0 = XBb + (size_t)(4*ib+p)*16*4096;
    const ushort_t* B1 = XBb + (size_t)(4*ib+p+2)*16*4096;
    const ushort_t* C0 = XCc + (size_t)(4*ib+p)*16*4096;
    const ushort_t* C1 = XCc + (size_t)(4*ib+p+2)*16*4096;
    for(int idx=tid; idx<256; idx+=128){
        int n=idx>>4, q=(idx&15)*4;
        ushort4 v0 = *reinterpret_cast<const ushort4*>(&B0[(size_t)n*4096 + l0 + q]);
        ushort4 v1 = *reinterpret_cast<const ushort4*>(&B1[(size_t)n*4096 + r0 + q]);
        ushort4 c0 = *reinterpret_cast<const ushort4*>(&C0[(size_t)n*4096 + l0 + q]);
        ushort4 c1 = *reinterpret_cast<const ushort4*>(&C1[(size_t)n*4096 + r0 + q]);
        sB[0][q+0][n]=b2f(v0.x); sB[0][q+1][n]=b2f(v0.y); sB[0][q+2][n]=b2f(v0.z); sB[0][q+3][n]=b2f(v0.w);
        sB[1][q+0][n]=b2f(v1.x); sB[1][q+1][n]=b2f(v1.y); sB[1][q+2][n]=b2f(v1.z); sB[1][q+3][n]=b2f(v1.w);
        sC[0][q+0][n]=b2f(c0.x); sC[0][q+1][n]=b2f(c0.y); sC[0][q+2][n]=b2f(c0.z); sC[0][q+3][n]=b2f(c0.w);
        sC[1][q+0][n]=b2f(c1.x); sC[1][q+1][n]=b2f(c1.y); sC[1][q+2][n]=b2f(c1.z); sC[1][q+3][n]=b2f(c1.w);
    }
    {
        const float* D0 = DT + (size_t)(4*ib+p)*2*4096;
        const float* D1 = DT + (size_t)(4*ib+p+2)*2*4096;
        int r=tid>>6, s=tid&63;
        sdt[0][s][r] = D0[(size_t)r*4096 + l0 + s];
        sdt[1][s][r] = D1[(size_t)r*4096 + r0 + s];
    }
    const ushort_t* U = (p?XCT:XC) + (size_t)ib*64*4096;
    for(int idx=tid; idx<1024; idx+=128){
        int rr=idx>>4, q=(idx&15)*4;
        *reinterpret_cast<ushort4*>(&su[rr*68+q]) =
            *reinterpret_cast<const ushort4*>(&U[(size_t)rr*4096 + l0 + q]);
    }
    __syncthreads();
    int k = p + 2*w;
    float dt0=dtw[(k*64+d)*2], dt1=dtw[(k*64+d)*2+1], db=dtb[k*64+d];
    float An[16];
    #pragma unroll
    for(int n=0;n<16;n++) An[n] = -__expf(A_logs[(k*64+d)*16+n]);
    float An0 = An[0];
    bool st = true;
    #pragma unroll
    for(int n=1;n<16;n++) st = st && (fabsf(An[n]-(n+1)*An0) <= 1e-4f*fabsf(An[n]) + 1e-6f);
    bool uni = (bool)__all((int)st);
    int chd = w ? 63-ch : ch;
    const ushort_t* e = CHS + ((size_t)(4*ib+k)*64 + chd)*1024 + d*16;
    float h[16];
    #pragma unroll
    for(int n=0;n<16;n++) h[n]=b2f(e[n]);

#define SCAN3_COMMON \
        float2 dtv = *reinterpret_cast<const float2*>(&sdt[w][s][0]); \
        float delta = softplusf(fmaf(dt0, dtv.x, fmaf(dt1, dtv.y, db))); \
        int j = w ? 63 - s : s; \
        float du = delta * b2f(su[d*68 + j]); \
        float bb[16]; float cc[16]; \
        { const float4* bp = reinterpret_cast<const float4*>(&sB[w][s][0]); \
          const float4* cp = reinterpret_cast<const float4*>(&sC[w][s][0]); \
          *reinterpret_cast<float4*>(&bb[0])  = bp[0]; \
          *reinterpret_cast<float4*>(&bb[4])  = bp[1]; \
          *reinterpret_cast<float4*>(&bb[8])  = bp[2]; \
          *reinterpret_cast<float4*>(&bb[12]) = bp[3]; \
          *reinterpret_cast<float4*>(&cc[0])  = cp[0]; \
          *reinterpret_cast<float4*>(&cc[4])  = cp[1]; \
          *reinterpret_cast<float4*>(&cc[8])  = cp[2]; \
          *reinterpret_cast<float4*>(&cc[12]) = cp[3]; }

    if(uni){
        for(int seg=0; seg<2; ++seg){
            for(int t=0; t<32; ++t){
                int s = seg*32 + t;
                SCAN3_COMMON
                float rr = __expf(delta*An0); float a = rr;
                float y=0.f;
                #pragma unroll
                for(int n=0;n<16;n++){
                    h[n] = fmaf(h[n], a, du*bb[n]);
                    y = fmaf(h[n], cc[n], y);
                    a *= rr;
                }
                if(seg==0) sy[d*68+j]=f2b(y);
                else       sy[d*68+j]=f2b(b2f(sy[d*68+j])+y);
            }
            __syncthreads();
        }
    } else {
        for(int seg=0; seg<2; ++seg){
            for(int t=0; t<32; ++t){
                int s = seg*32 + t;
                SCAN3_COMMON
                float y=0.f;
                #pragma unroll
                for(int n=0;n<16;n++){
                    float a = __expf(delta*An[n]);
                    h[n] = fmaf(h[n], a, du*bb[n]);
                    y = fmaf(h[n], cc[n], y);
                }
                if(seg==0) sy[d*68+j]=f2b(y);
                else       sy[d*68+j]=f2b(b2f(sy[d*68+j])+y);
            }
            __syncthreads();
        }
    }
#undef SCAN3_COMMON
    ushort_t* Yb = (p?Y2:Y1) + (size_t)ib*64*4096;
    for(int idx=tid; idx<1024; idx+=128){
        int rr=idx>>4, q=(idx&15)*4;
        *reinterpret_cast<ushort4*>(&Yb[(size_t)rr*4096 + l0 + q]) =
            *reinterpret_cast<const ushort4*>(&sy[rr*68+q]);
    }
}

// ---- K8: out-LN(64) + gate + out-proj (64->32) + residual + scale + BN + ReLU (f32 out)
//      also folds the Ds*u term: y += (sum_k D_k)[d] * XC[d][l] ----
__global__ __launch_bounds__(256) void k_final(const ushort_t* __restrict__ Y1, const ushort_t* __restrict__ Y2T,
        const ushort_t* __restrict__ ZS, const float* __restrict__ Y0,
        const ushort_t* __restrict__ XC, const float* __restrict__ Ds,
        const float* __restrict__ on_g, const float* __restrict__ on_b,
        const float* __restrict__ out_w,
        const float* __restrict__ s1, const float* __restrict__ s2, const float* __restrict__ s3,
        const float* __restrict__ bn_g, const float* __restrict__ bn_b,
        float* __restrict__ out){
    __shared__ float W[32*64];
    __shared__ float sD[64];
    int tid=threadIdx.x;
    for(int idx=tid; idx<2048; idx+=256) W[idx]=out_w[idx];
    if(tid<64) sD[tid]=Ds[tid]+Ds[64+tid]+Ds[128+tid]+Ds[192+tid];
    __syncthreads();
    int pg=blockIdx.x*256+tid;
    int ib=pg>>12, p=pg&4095;
    int i=ib>>3, b=ib&7;
    float y[64];
    const ushort_t* y1 = Y1 + (size_t)ib*64*4096 + p;
    const ushort_t* y2 = Y2T + (size_t)ib*64*4096 + p;
    const ushort_t* xc = XC + (size_t)ib*64*4096 + p;
    float mu=0.f;
    #pragma unroll
    for(int dd=0;dd<64;dd++){
        y[dd]=b2f(y1[(size_t)dd*4096])+b2f(y2[(size_t)dd*4096])+sD[dd]*b2f(xc[(size_t)dd*4096]);
        mu+=y[dd];
    }
    mu*=(1.f/64.f);
    float v=0.f;
    #pragma unroll
    for(int dd=0;dd<64;dd++){ float q=y[dd]-mu; v+=q*q; }
    v*=(1.f/64.f);
    float rs=rsqrtf(v+1e-5f);
    const ushort_t* zs = ZS + (size_t)ib*64*4096 + p;
    #pragma unroll
    for(int dd=0;dd<64;dd++){
        float yn=(y[dd]-mu)*rs*on_g[dd]+on_b[dd];
        y[dd]=yn*b2f(zs[(size_t)dd*4096]);
    }
    float sc = (i==0)?s1[0]:((i==1)?s2[0]:s3[0]);
    const float inv = rsqrtf(1.00001f);
    const float* y0 = Y0 + (size_t)ib*32*4096 + p;
    for(int c=0;c<32;c++){
        float a=0.f;
        #pragma unroll
        for(int dd=0;dd<64;dd++) a=fmaf(y[dd],W[c*64+dd],a);
        float o=(y0[(size_t)c*4096]+a)*sc;
        int chn=i*32+c;
        float vv=fmaf(o*inv, bn_g[chn], bn_b[chn]);
        out[((size_t)b*128+chn)*4096 + p]=fmaxf(vv,0.f);
    }
}

// ---- K9: branch 4 passthrough * scale4 + BN + ReLU (f32 out) ----
__global__ __launch_bounds__(256) void k_branch4(const float* __restrict__ x,
        const float* __restrict__ s4, const float* __restrict__ bn_g,
        const float* __restrict__ bn_b, float* __restrict__ out){
    int g=blockIdx.x*256+threadIdx.x;
    int b=g>>17; int rem=g&131071; int c=rem>>12; int p=rem&4095;
    int chn=96+c;
    const float inv=rsqrtf(1.00001f);
    float v=x[((size_t)b*128+chn)*4096+p]*s4[0];
    v=fmaf(v*inv, bn_g[chn], bn_b[chn]);
    out[((size_t)b*128+chn)*4096+p]=fmaxf(v,0.f);
}

extern "C" void kernel_launch(void* const* d_in, const int* in_sizes, int n_in,
                              void* d_out, int out_size, void* d_ws, size_t ws_size,
                              hipStream_t stream) {
    const float* x      = (const float*)d_in[0];
    const float* ln_g   = (const float*)d_in[16];
    const float* ln_b   = (const float*)d_in[17];
    const float* in_w   = (const float*)d_in[18];
    const float* conv_w = (const float*)d_in[19];
    const float* conv_b = (const float*)d_in[20];
    const float* xproj  = (const float*)d_in[21];
    const float* dtw    = (const float*)d_in[22];
    const float* dtb    = (const float*)d_in[23];
    const float* A_logs = (const float*)d_in[24];
    const float* Ds     = (const float*)d_in[25];
    const float* on_g   = (const float*)d_in[26];
    const float* on_b   = (const float*)d_in[27];
    const float* out_w  = (const float*)d_in[28];
    const float* sc1    = (const float*)d_in[29];
    const float* sc2    = (const float*)d_in[30];
    const float* sc3    = (const float*)d_in[31];
    const float* sc4    = (const float*)d_in[32];
    const float* bn_g   = (const float*)d_in[33];
    const float* bn_b   = (const float*)d_in[34];

    AxialParams P;
    for(int i=0;i<3;i++){
        P.kh[i]=(const float*)d_in[1+5*i];
        P.kw[i]=(const float*)d_in[2+5*i];
        P.k3[i]=(const float*)d_in[3+5*i];
        P.g[i] =(const float*)d_in[4+5*i];
        P.b[i] =(const float*)d_in[5+5*i];
    }

    // ---- workspace layout (bytes); total ~118 MB ----
    char* base = (char*)d_ws;
    float*    Y0   = (float*)   (base + 0);            // 12,582,912 f32
    ushort_t* ZS   = (ushort_t*)(base + 12582912);     // bf16
    ushort_t* XC   = (ushort_t*)(base + 25165824);     // bf16
    ushort_t* XCT  = (ushort_t*)(base + 37748736);     // bf16
    ushort_t* XBb  = (ushort_t*)(base + 50331648);     // bf16 (16 B rows); early alias: XW
    ushort_t* XW   = (ushort_t*)(base + 50331648);     // alias (dead before k_xdbl writes)
    ushort_t* XCc  = (ushort_t*)(base + 62914560);     // bf16 (16 C rows)
    float*    DT   = (float*)   (base + 75497472);     // f32 (2 delta rows)
    ushort_t* CHS  = (ushort_t*)(base + 78643200);     // bf16
    float*    SD   = (float*)   (base + 91226112);     // f32
    ushort_t* Y1   = (ushort_t*)(base + 92798976);     // bf16
    ushort_t* Y2   = (ushort_t*)(base + 105381888);    // bf16 (end 117,964,800)
    ushort_t* Y2T  = XBb;                              // alias (XBb dead after scan3)

    float* out = (float*)d_out;

    k_axial    <<<768,   256, 0, stream>>>(x, Y0, P);
    k_lnproj   <<<384,   256, 0, stream>>>(Y0, ln_g, ln_b, in_w, XW, ZS);
    k_dwsilu   <<<24576, 256, 0, stream>>>(XW, conv_w, conv_b, XC);
    k_transpose<<<1536,  256, 0, stream>>>(XC, XCT);
    k_xdbl     <<<1536,  256, 0, stream>>>(XC, XCT, xproj, XBb, XCc, DT);
    k_scan1    <<<3072,  128, 0, stream>>>(XBb, DT, XC, XCT, dtw, dtb, A_logs, CHS, SD);
    k_scan2    <<<96,   1024, 0, stream>>>(A_logs, SD, CHS);
    k_scan3    <<<3072,  128, 0, stream>>>(XBb, XCc, DT, XC, XCT, dtw, dtb, A_logs, CHS, Y1, Y2);
    k_transpose<<<1536,  256, 0, stream>>>(Y2, Y2T);
    k_final    <<<384,   256, 0, stream>>>(Y1, Y2T, ZS, Y0, XC, Ds, on_g, on_b, out_w,
                                           sc1, sc2, sc3, bn_g, bn_b, out);
    k_branch4  <<<4096,  256, 0, stream>>>(x, sc4, bn_g, bn_b, out);
}

// Round 5
// 286.609 us; speedup vs baseline: 2.1971x; 1.6385x over previous
//
#include <hip/hip_runtime.h>
#include <hip/hip_bf16.h>
#include <cstdint>

typedef unsigned short ushort_t;
typedef float f32x2 __attribute__((ext_vector_type(2)));

__device__ __forceinline__ float softplus2(float x){
    return fmaxf(x, 0.f) + __logf(1.f + __expf(-fabsf(x)));
}
__device__ __forceinline__ float siluf(float x){
    return x / (1.f + __expf(-x));
}
__device__ __forceinline__ float b2f(ushort_t u){
    union { uint32_t i; float f; } v; v.i = ((uint32_t)u)<<16; return v.f;
}
__device__ __forceinline__ ushort_t f2b(float f){
    uint32_t x = __float_as_uint(f);
    uint32_t r = (x + 0x7FFFu + ((x>>16)&1u)) >> 16;
    return (ushort_t)r;
}

struct AxialParams {
    const float* kh[3]; const float* kw[3]; const float* k3[3];
    const float* g[3];  const float* b[3];
};

// ---- K1: axial depthwise chain (kw -> kh -> 3x3) + BN + residual (f32 in, f32 out) ----
__global__ __launch_bounds__(256) void k_axial(const float* __restrict__ x,
                                               float* __restrict__ Y0, AxialParams P){
    __shared__ float s0[4096];
    __shared__ float s1[4096];
    int bid = blockIdx.x;
    int i = bid >> 8;
    int rem = bid & 255;
    int b = rem >> 5, c = rem & 31;
    int dil = i + 1;
    const float* xin = x + ((size_t)(b*128 + i*32 + c))*4096;
    float wkw[7], wkh[7], wk3[9];
    #pragma unroll
    for(int t=0;t<7;t++){ wkw[t]=P.kw[i][c*7+t]; wkh[t]=P.kh[i][c*7+t]; }
    #pragma unroll
    for(int t=0;t<9;t++) wk3[t]=P.k3[i][c*9+t];
    float gc = P.g[i][c], bc = P.b[i][c];
    int tid = threadIdx.x;
    for(int idx=tid; idx<4096; idx+=256) s0[idx]=xin[idx];
    __syncthreads();
    for(int idx=tid; idx<4096; idx+=256){
        int h=idx>>6, w=idx&63; float a=0.f;
        #pragma unroll
        for(int t=0;t<7;t++){ int ww=w+(t-3)*dil; if(ww>=0&&ww<64) a=fmaf(s0[h*64+ww],wkw[t],a); }
        s1[idx]=a;
    }
    __syncthreads();
    for(int idx=tid; idx<4096; idx+=256){
        int h=idx>>6, w=idx&63; float a=0.f;
        #pragma unroll
        for(int t=0;t<7;t++){ int hh=h+(t-3)*dil; if(hh>=0&&hh<64) a=fmaf(s1[hh*64+w],wkh[t],a); }
        s0[idx]=a;
    }
    __syncthreads();
    const float inv = rsqrtf(1.00001f);
    float* out = Y0 + ((size_t)(i*8+b)*32 + c)*4096;
    for(int idx=tid; idx<4096; idx+=256){
        int h=idx>>6, w=idx&63; float a=0.f;
        #pragma unroll
        for(int t=0;t<9;t++){
            int hh=h+((t/3)-1)*dil, ww=w+((t%3)-1)*dil;
            if(hh>=0&&hh<64&&ww>=0&&ww<64) a=fmaf(s0[hh*64+ww],wk3[t],a);
        }
        out[idx] = a*inv*gc + bc + xin[idx];
    }
}

// ---- K2: channel LayerNorm(32) + in_proj (32->128) -> XW (bf16), ZS = silu(z) (bf16) ----
__global__ __launch_bounds__(256) void k_lnproj(const float* __restrict__ Y0,
        const float* __restrict__ ln_g, const float* __restrict__ ln_b,
        const float* __restrict__ in_w, ushort_t* __restrict__ XW, ushort_t* __restrict__ ZS){
    __shared__ float W[128*32];
    int tid=threadIdx.x;
    for(int idx=tid; idx<4096; idx+=256) W[idx]=in_w[idx];
    __syncthreads();
    int pg = blockIdx.x*256 + tid;
    int ib = pg>>12, p = pg&4095;
    const float* src = Y0 + (size_t)ib*32*4096;
    float t[32];
    float mu=0.f;
    #pragma unroll
    for(int c=0;c<32;c++){ t[c]=src[c*4096+p]; mu+=t[c]; }
    mu *= (1.f/32.f);
    float v=0.f;
    #pragma unroll
    for(int c=0;c<32;c++){ float d=t[c]-mu; v+=d*d; }
    v *= (1.f/32.f);
    float rs = rsqrtf(v+1e-5f);
    #pragma unroll
    for(int c=0;c<32;c++) t[c] = (t[c]-mu)*rs*ln_g[c] + ln_b[c];
    ushort_t* xw = XW + (size_t)ib*64*4096 + p;
    ushort_t* zs = ZS + (size_t)ib*64*4096 + p;
    for(int j=0;j<64;j++){
        float a=0.f, a2=0.f;
        #pragma unroll
        for(int c=0;c<32;c++){
            a  = fmaf(t[c], W[j*32+c],      a);
            a2 = fmaf(t[c], W[(j+64)*32+c], a2);
        }
        xw[(size_t)j*4096] = f2b(a);
        zs[(size_t)j*4096] = f2b(siluf(a2));
    }
}

// ---- K3: fused depthwise 3x3 + bias + silu -> XC AND XCT (transposed) ----
__global__ __launch_bounds__(256) void k_dwt(const ushort_t* __restrict__ XW,
        const float* __restrict__ cw, const float* __restrict__ cb,
        ushort_t* __restrict__ XC, ushort_t* __restrict__ XCT){
    __shared__ ushort_t sin_[4096];
    __shared__ ushort_t tr[64*66];
    int bid=blockIdx.x, tid=threadIdx.x;
    int d = bid&63;
    const ushort_t* src = XW + (size_t)bid*4096;
    for(int idx=tid; idx<1024; idx+=256)
        *reinterpret_cast<ushort4*>(&sin_[idx*4]) = *reinterpret_cast<const ushort4*>(&src[idx*4]);
    float wk[9];
    #pragma unroll
    for(int t=0;t<9;t++) wk[t]=cw[d*9+t];
    float bias=cb[d];
    __syncthreads();
    ushort_t* outp = XC + (size_t)bid*4096;
    for(int idx=tid; idx<4096; idx+=256){
        int h=idx>>6, wq=idx&63;
        float a=bias;
        #pragma unroll
        for(int t=0;t<9;t++){
            int hh=h+(t/3)-1, ww=wq+(t%3)-1;
            if(hh>=0&&hh<64&&ww>=0&&ww<64) a=fmaf(b2f(sin_[hh*64+ww]),wk[t],a);
        }
        ushort_t vb = f2b(siluf(a));
        outp[idx]=vb;
        tr[wq*66+h]=vb;
    }
    __syncthreads();
    ushort_t* outt = XCT + (size_t)bid*4096;
    for(int idx=tid; idx<4096; idx+=256){
        outt[idx]=tr[(idx>>6)*66+(idx&63)];
    }
}

// ---- transpose 64x64 bf16 planes (Y2 -> Y2T) ----
__global__ __launch_bounds__(256) void k_transpose(const ushort_t* __restrict__ src, ushort_t* __restrict__ dst){
    __shared__ ushort_t tile[64*66];
    size_t plane = blockIdx.x;
    const ushort_t* s = src + plane*4096;
    ushort_t* d = dst + plane*4096;
    int tid=threadIdx.x;
    for(int idx=tid; idx<4096; idx+=256){
        int h=idx>>6, w=idx&63;
        tile[w*66+h]=s[idx];
    }
    __syncthreads();
    for(int idx=tid; idx<4096; idx+=256){
        d[idx]=tile[(idx>>6)*66 + (idx&63)];
    }
}

// ---- K4: x_dbl rows: delta rows (2) -> DT f32; B rows -> XBb bf16; C rows -> XCc bf16 ----
__global__ __launch_bounds__(256) void k_xdbl(const ushort_t* __restrict__ XC, const ushort_t* __restrict__ XCT,
        const float* __restrict__ xproj, ushort_t* __restrict__ XBb, ushort_t* __restrict__ XCc,
        float* __restrict__ DT){
    __shared__ float Wt[64][36];
    int bid=blockIdx.x; int tid=threadIdx.x;
    int ibk = bid>>4; int lb = bid&15;
    int k = ibk & 3; int ib = ibk>>2;
    for(int idx=tid; idx<2176; idx+=256){
        int c=idx>>6, dd=idx&63;
        Wt[dd][c]=xproj[k*2176+idx];
    }
    __syncthreads();
    int l = lb*256+tid;
    const ushort_t* src = ((k&1)?XCT:XC) + (size_t)ib*64*4096;
    int idxl = (k&2)? (4095-l) : l;
    float acc[34];
    #pragma unroll
    for(int c=0;c<34;c++) acc[c]=0.f;
    for(int dd=0;dd<64;dd++){
        float u = b2f(src[(size_t)dd*4096 + idxl]);
        float wv[36];
        const float4* wp = reinterpret_cast<const float4*>(&Wt[dd][0]);
        *reinterpret_cast<float4*>(&wv[0])  = wp[0];
        *reinterpret_cast<float4*>(&wv[4])  = wp[1];
        *reinterpret_cast<float4*>(&wv[8])  = wp[2];
        *reinterpret_cast<float4*>(&wv[12]) = wp[3];
        *reinterpret_cast<float4*>(&wv[16]) = wp[4];
        *reinterpret_cast<float4*>(&wv[20]) = wp[5];
        *reinterpret_cast<float4*>(&wv[24]) = wp[6];
        *reinterpret_cast<float4*>(&wv[28]) = wp[7];
        *reinterpret_cast<float2*>(&wv[32]) = *reinterpret_cast<const float2*>(&Wt[dd][32]);
        #pragma unroll
        for(int c=0;c<34;c++) acc[c] = fmaf(u, wv[c], acc[c]);
    }
    DT[((size_t)ibk*2)*4096 + l]   = acc[0];
    DT[((size_t)ibk*2+1)*4096 + l] = acc[1];
    ushort_t* ob = XBb + ((size_t)ibk*16)*4096 + l;
    ushort_t* oc = XCc + ((size_t)ibk*16)*4096 + l;
    #pragma unroll
    for(int c=0;c<16;c++){
        ob[(size_t)c*4096]=f2b(acc[2+c]);
        oc[(size_t)c*4096]=f2b(acc[18+c]);
    }
}

// ================= scan kernels =================

template<bool UNI>
__device__ __forceinline__ void scan1_body(int w,int d,float dt0,float dt1,float db,
    const float* An, f32x2* h2, float& S,
    const float (*sB)[64][16], const float (*sdt)[64][2], const ushort_t (*su)[66])
{
    for(int s=0;s<64;s++){
        const float* dp=&sdt[w][s][0];
        float delta=softplus2(fmaf(dt0,dp[0],fmaf(dt1,dp[1],db)));
        S+=delta;
        int j = w? 63-s : s;
        float du = delta*b2f(su[j][d]);
        float bb[16];
        const float4* bp=reinterpret_cast<const float4*>(&sB[w][s][0]);
        reinterpret_cast<float4*>(bb)[0]=bp[0];
        reinterpret_cast<float4*>(bb)[1]=bp[1];
        reinterpret_cast<float4*>(bb)[2]=bp[2];
        reinterpret_cast<float4*>(bb)[3]=bp[3];
        if(UNI){
            float r1=__expf(delta*An[0]);
            f32x2 a={r1,r1*r1}, rq={r1*r1,r1*r1}, du2={du,du};
            const f32x2* b2p=reinterpret_cast<const f32x2*>(bb);
            #pragma unroll
            for(int i=0;i<8;i++){ h2[i]=h2[i]*a+du2*b2p[i]; a=a*rq; }
        } else {
            float* hf=reinterpret_cast<float*>(h2);
            #pragma unroll
            for(int n=0;n<16;n++){ float a=__expf(delta*An[n]); hf[n]=fmaf(hf[n],a,du*bb[n]); }
        }
    }
}

// block=(ib,p,ch); wave0 = dir k=p (fwd), wave1 = dir k=p+2 (bwd, same spatial tile)
__global__ __launch_bounds__(128) void k_scan1(const ushort_t* __restrict__ XBb, const float* __restrict__ DT,
        const ushort_t* __restrict__ XC, const ushort_t* __restrict__ XCT,
        const float* __restrict__ dtw, const float* __restrict__ dtb,
        const float* __restrict__ A_logs,
        ushort_t* __restrict__ CHS, float* __restrict__ SD){
    __shared__ float sB[2][64][16];     // [w][scan-step][n]
    __shared__ float sdt[2][64][2];
    __shared__ ushort_t su[64][66];     // [j spatial][d]
    int bid=blockIdx.x, tid=threadIdx.x;
    int ib = bid>>7; int rem = bid&127; int p = rem>>6; int ch = rem&63;
    int w = tid>>6, d = tid&63;
    int l0 = ch*64, r0 = 4032 - l0;
    const ushort_t* B0 = XBb + (size_t)(4*ib+p)*16*4096;
    const ushort_t* B1 = XBb + (size_t)(4*ib+p+2)*16*4096;
    for(int idx=tid; idx<512; idx+=128){
        int w2=idx>>8, n=(idx>>4)&15, q=(idx&15)*4;
        const ushort_t* Bs = w2? B1 : B0;
        int base = (w2? r0 : l0) + q;
        ushort4 v = *reinterpret_cast<const ushort4*>(&Bs[(size_t)n*4096 + base]);
        sB[w2][q+0][n]=b2f(v.x); sB[w2][q+1][n]=b2f(v.y); sB[w2][q+2][n]=b2f(v.z); sB[w2][q+3][n]=b2f(v.w);
    }
    {
        const float* D0 = DT + (size_t)(4*ib+p)*2*4096;
        const float* D1 = DT + (size_t)(4*ib+p+2)*2*4096;
        int r=tid>>6, s=tid&63;
        sdt[0][s][r] = D0[(size_t)r*4096 + l0 + s];
        sdt[1][s][r] = D1[(size_t)r*4096 + r0 + s];
    }
    const ushort_t* U = (p?XCT:XC) + (size_t)ib*64*4096;
    for(int idx=tid; idx<1024; idx+=128){
        int r=idx>>4, q=(idx&15)*4;
        ushort4 v = *reinterpret_cast<const ushort4*>(&U[(size_t)r*4096 + l0 + q]);
        su[q+0][r]=v.x; su[q+1][r]=v.y; su[q+2][r]=v.z; su[q+3][r]=v.w;
    }
    __syncthreads();
    int k = p + 2*w;
    float dt0=dtw[(k*64+d)*2], dt1=dtw[(k*64+d)*2+1], db=dtb[k*64+d];
    float An[16];
    #pragma unroll
    for(int n=0;n<16;n++) An[n] = -__expf(A_logs[(k*64+d)*16+n]);
    bool st = true;
    #pragma unroll
    for(int n=1;n<16;n++) st = st && (fabsf(An[n]-(n+1)*An[0]) <= 1e-4f*fabsf(An[n]) + 1e-6f);
    bool uni = (bool)__all((int)st);
    f32x2 h2[8];
    #pragma unroll
    for(int i=0;i<8;i++){ h2[i].x=0.f; h2[i].y=0.f; }
    float S=0.f;
    if(uni) scan1_body<true >(w,d,dt0,dt1,db,An,h2,S,sB,sdt,su);
    else    scan1_body<false>(w,d,dt0,dt1,db,An,h2,S,sB,sdt,su);
    int chd = w ? 63-ch : ch;
    ushort_t* o = CHS + ((size_t)(4*ib+k)*64 + chd)*1024 + d*16;
    const float* hf = reinterpret_cast<const float*>(h2);
    #pragma unroll
    for(int n=0;n<16;n++) o[n]=f2b(hf[n]);
    SD[((size_t)(4*ib+k)*64 + chd)*64 + d]=S;
}

// ---- K5b: chunk-level exclusive scan (64 chunks, scan order) ----
__global__ __launch_bounds__(1024) void k_scan2(const float* __restrict__ A_logs,
        const float* __restrict__ SD, ushort_t* __restrict__ CHS){
    __shared__ float sS[4096];
    int ibk=blockIdx.x; int tid=threadIdx.x;
    for(int idx=tid; idx<4096; idx+=1024) sS[idx]=SD[(size_t)ibk*4096+idx];
    __syncthreads();
    int d=tid>>4, n=tid&15, k=ibk&3;
    float An = -__expf(A_logs[(k*64+d)*16+n]);
    float H=0.f;
    for(int c=0;c<64;c++){
        float pc = __expf(An*sS[c*64+d]);
        size_t o = ((size_t)ibk*64+c)*1024 + tid;
        float loc = b2f(CHS[o]);
        CHS[o]=f2b(H);
        H = fmaf(H, pc, loc);
    }
}

// seg staging helpers for scan3 (idx in [0,512): arr=B/C, w2, n, qi)
__device__ __forceinline__ const ushort_t* seg_src(int idx, int seg,
        const ushort_t* B0, const ushort_t* B1, const ushort_t* C0, const ushort_t* C1,
        int l0, int r0){
    int arr=idx>>8, w2=(idx>>7)&1, n=(idx>>3)&15, qi=idx&7;
    const ushort_t* S = arr? (w2?C1:C0) : (w2?B1:B0);
    int base = (w2? r0 : l0) + seg*32 + qi*4;
    return &S[(size_t)n*4096 + base];
}
__device__ __forceinline__ void seg_wr(int idx, ushort4 v,
        float (*sB)[32][16], float (*sC)[32][16]){
    int arr=idx>>8, w2=(idx>>7)&1, n=(idx>>3)&15, qi=idx&7;
    float (*dst)[32][16] = arr? sC : sB;
    int sl=qi*4;
    dst[w2][sl+0][n]=b2f(v.x); dst[w2][sl+1][n]=b2f(v.y);
    dst[w2][sl+2][n]=b2f(v.z); dst[w2][sl+3][n]=b2f(v.w);
}

template<bool UNI, int SEG>
__device__ __forceinline__ void scan3_seg(int w,int d,float dt0,float dt1,float db,
    const float* An, f32x2* h2,
    const float (*sB)[32][16], const float (*sC)[32][16],
    const float (*sdt)[64][2], const ushort_t (*su)[66], ushort_t (*sy)[66])
{
    for(int t=0;t<32;t++){
        int s = SEG*32 + t;
        const float* dp=&sdt[w][s][0];
        float delta=softplus2(fmaf(dt0,dp[0],fmaf(dt1,dp[1],db)));
        int j = w? 63-s : s;
        float du = delta*b2f(su[j][d]);
        float bb[16], cc[16];
        const float4* bp=reinterpret_cast<const float4*>(&sB[w][t][0]);
        const float4* cp=reinterpret_cast<const float4*>(&sC[w][t][0]);
        reinterpret_cast<float4*>(bb)[0]=bp[0]; reinterpret_cast<float4*>(bb)[1]=bp[1];
        reinterpret_cast<float4*>(bb)[2]=bp[2]; reinterpret_cast<float4*>(bb)[3]=bp[3];
        reinterpret_cast<float4*>(cc)[0]=cp[0]; reinterpret_cast<float4*>(cc)[1]=cp[1];
        reinterpret_cast<float4*>(cc)[2]=cp[2]; reinterpret_cast<float4*>(cc)[3]=cp[3];
        float y;
        if(UNI){
            float r1=__expf(delta*An[0]);
            f32x2 a={r1,r1*r1}, rq={r1*r1,r1*r1}, du2={du,du};
            f32x2 y2={0.f,0.f};
            const f32x2* b2p=reinterpret_cast<const f32x2*>(bb);
            const f32x2* c2p=reinterpret_cast<const f32x2*>(cc);
            #pragma unroll
            for(int i=0;i<8;i++){
                h2[i]=h2[i]*a+du2*b2p[i];
                y2=y2+h2[i]*c2p[i];
                a=a*rq;
            }
            y = y2.x + y2.y;
        } else {
            y=0.f;
            float* hf=reinterpret_cast<float*>(h2);
            #pragma unroll
            for(int n=0;n<16;n++){
                float a=__expf(delta*An[n]);
                hf[n]=fmaf(hf[n],a,du*bb[n]);
                y=fmaf(hf[n],cc[n],y);
            }
        }
        if(SEG==0) sy[j][d]=f2b(y);
        else       sy[j][d]=f2b(b2f(sy[j][d])+y);
    }
}

__global__ __launch_bounds__(128) void k_scan3(const ushort_t* __restrict__ XBb, const ushort_t* __restrict__ XCc,
        const float* __restrict__ DT,
        const ushort_t* __restrict__ XC, const ushort_t* __restrict__ XCT,
        const float* __restrict__ dtw, const float* __restrict__ dtb,
        const float* __restrict__ A_logs,
        const ushort_t* __restrict__ CHS,
        ushort_t* __restrict__ Y1, ushort_t* __restrict__ Y2){
    __shared__ float sB[2][32][16];
    __shared__ float sC[2][32][16];
    __shared__ float sdt[2][64][2];
    __shared__ ushort_t su[64][66];
    __shared__ ushort_t sy[64][66];
    int bid=blockIdx.x, tid=threadIdx.x;
    int ib = bid>>7; int rem = bid&127; int p = rem>>6; int ch = rem&63;
    int w = tid>>6, d = tid&63;
    int l0 = ch*64, r0 = 4032 - l0;
    const ushort_t* B0 = XBb + (size_t)(4*ib+p)*16*4096;
    const ushort_t* B1 = XBb + (size_t)(4*ib+p+2)*16*4096;
    const ushort_t* C0 = XCc + (size_t)(4*ib+p)*16*4096;
    const ushort_t* C1 = XCc + (size_t)(4*ib+p+2)*16*4096;
    // stage seg0 B/C
    for(int idx=tid; idx<512; idx+=128)
        seg_wr(idx, *reinterpret_cast<const ushort4*>(seg_src(idx,0,B0,B1,C0,C1,l0,r0)), sB, sC);
    {
        const float* D0 = DT + (size_t)(4*ib+p)*2*4096;
        const float* D1 = DT + (size_t)(4*ib+p+2)*2*4096;
        int r=tid>>6, s=tid&63;
        sdt[0][s][r] = D0[(size_t)r*4096 + l0 + s];
        sdt[1][s][r] = D1[(size_t)r*4096 + r0 + s];
    }
    const ushort_t* U = (p?XCT:XC) + (size_t)ib*64*4096;
    for(int idx=tid; idx<1024; idx+=128){
        int r=idx>>4, q=(idx&15)*4;
        ushort4 v = *reinterpret_cast<const ushort4*>(&U[(size_t)r*4096 + l0 + q]);
        su[q+0][r]=v.x; su[q+1][r]=v.y; su[q+2][r]=v.z; su[q+3][r]=v.w;
    }
    __syncthreads();
    // prefetch seg1 B/C into regs (hides HBM/L2 latency under seg0 compute)
    ushort4 pf[4];
    #pragma unroll
    for(int r=0;r<4;r++)
        pf[r] = *reinterpret_cast<const ushort4*>(seg_src(tid+r*128,1,B0,B1,C0,C1,l0,r0));
    int k = p + 2*w;
    float dt0=dtw[(k*64+d)*2], dt1=dtw[(k*64+d)*2+1], db=dtb[k*64+d];
    float An[16];
    #pragma unroll
    for(int n=0;n<16;n++) An[n] = -__expf(A_logs[(k*64+d)*16+n]);
    bool st = true;
    #pragma unroll
    for(int n=1;n<16;n++) st = st && (fabsf(An[n]-(n+1)*An[0]) <= 1e-4f*fabsf(An[n]) + 1e-6f);
    bool uni = (bool)__all((int)st);
    int chd = w ? 63-ch : ch;
    const ushort_t* e = CHS + ((size_t)(4*ib+k)*64 + chd)*1024 + d*16;
    f32x2 h2[8];
    {
        float* hf = reinterpret_cast<float*>(h2);
        #pragma unroll
        for(int n=0;n<16;n++) hf[n]=b2f(e[n]);
    }
    if(uni) scan3_seg<true ,0>(w,d,dt0,dt1,db,An,h2,sB,sC,sdt,su,sy);
    else    scan3_seg<false,0>(w,d,dt0,dt1,db,An,h2,sB,sC,sdt,su,sy);
    __syncthreads();
    #pragma unroll
    for(int r=0;r<4;r++) seg_wr(tid+r*128, pf[r], sB, sC);
    __syncthreads();
    if(uni) scan3_seg<true ,1>(w,d,dt0,dt1,db,An,h2,sB,sC,sdt,su,sy);
    else    scan3_seg<false,1>(w,d,dt0,dt1,db,An,h2,sB,sC,sdt,su,sy);
    __syncthreads();
    ushort_t* Yb = (p?Y2:Y1) + (size_t)ib*64*4096;
    for(int idx=tid; idx<1024; idx+=128){
        int r=idx>>4, q=(idx&15)*4;
        ushort4 v;
        v.x=sy[q+0][r]; v.y=sy[q+1][r]; v.z=sy[q+2][r]; v.w=sy[q+3][r];
        *reinterpret_cast<ushort4*>(&Yb[(size_t)r*4096 + l0 + q]) = v;
    }
}

// ---- K8: out-LN(64) + gate + out-proj (64->32) + residual + scale + BN + ReLU (f32 out)
//      also folds the Ds*u term: y += (sum_k D_k)[d] * XC[d][l] ----
__global__ __launch_bounds__(256) void k_final(const ushort_t* __restrict__ Y1, const ushort_t* __restrict__ Y2T,
        const ushort_t* __restrict__ ZS, const float* __restrict__ Y0,
        const ushort_t* __restrict__ XC, const float* __restrict__ Ds,
        const float* __restrict__ on_g, const float* __restrict__ on_b,
        const float* __restrict__ out_w,
        const float* __restrict__ s1, const float* __restrict__ s2, const float* __restrict__ s3,
        const float* __restrict__ bn_g, const float* __restrict__ bn_b,
        float* __restrict__ out){
    __shared__ float W[32*64];
    __shared__ float sD[64];
    int tid=threadIdx.x;
    for(int idx=tid; idx<2048; idx+=256) W[idx]=out_w[idx];
    if(tid<64) sD[tid]=Ds[tid]+Ds[64+tid]+Ds[128+tid]+Ds[192+tid];
    __syncthreads();
    int pg=blockIdx.x*256+tid;
    int ib=pg>>12, p=pg&4095;
    int i=ib>>3, b=ib&7;
    float y[64];
    const ushort_t* y1 = Y1 + (size_t)ib*64*4096 + p;
    const ushort_t* y2 = Y2T + (size_t)ib*64*4096 + p;
    const ushort_t* xc = XC + (size_t)ib*64*4096 + p;
    float mu=0.f;
    #pragma unroll
    for(int dd=0;dd<64;dd++){
        y[dd]=b2f(y1[(size_t)dd*4096])+b2f(y2[(size_t)dd*4096])+sD[dd]*b2f(xc[(size_t)dd*4096]);
        mu+=y[dd];
    }
    mu*=(1.f/64.f);
    float v=0.f;
    #pragma unroll
    for(int dd=0;dd<64;dd++){ float q=y[dd]-mu; v+=q*q; }
    v*=(1.f/64.f);
    float rs=rsqrtf(v+1e-5f);
    const ushort_t* zs = ZS + (size_t)ib*64*4096 + p;
    #pragma unroll
    for(int dd=0;dd<64;dd++){
        float yn=(y[dd]-mu)*rs*on_g[dd]+on_b[dd];
        y[dd]=yn*b2f(zs[(size_t)dd*4096]);
    }
    float sc = (i==0)?s1[0]:((i==1)?s2[0]:s3[0]);
    const float inv = rsqrtf(1.00001f);
    const float* y0 = Y0 + (size_t)ib*32*4096 + p;
    for(int c=0;c<32;c++){
        float a=0.f;
        #pragma unroll
        for(int dd=0;dd<64;dd++) a=fmaf(y[dd],W[c*64+dd],a);
        float o=(y0[(size_t)c*4096]+a)*sc;
        int chn=i*32+c;
        float vv=fmaf(o*inv, bn_g[chn], bn_b[chn]);
        out[((size_t)b*128+chn)*4096 + p]=fmaxf(vv,0.f);
    }
}

// ---- K9: branch 4 passthrough * scale4 + BN + ReLU (f32 out) ----
__global__ __launch_bounds__(256) void k_branch4(const float* __restrict__ x,
        const float* __restrict__ s4, const float* __restrict__ bn_g,
        const float* __restrict__ bn_b, float* __restrict__ out){
    int g=blockIdx.x*256+threadIdx.x;
    int b=g>>17; int rem=g&131071; int c=rem>>12; int p=rem&4095;
    int chn=96+c;
    const float inv=rsqrtf(1.00001f);
    float v=x[((size_t)b*128+chn)*4096+p]*s4[0];
    v=fmaf(v*inv, bn_g[chn], bn_b[chn]);
    out[((size_t)b*128+chn)*4096+p]=fmaxf(v,0.f);
}

extern "C" void kernel_launch(void* const* d_in, const int* in_sizes, int n_in,
                              void* d_out, int out_size, void* d_ws, size_t ws_size,
                              hipStream_t stream) {
    const float* x      = (const float*)d_in[0];
    const float* ln_g   = (const float*)d_in[16];
    const float* ln_b   = (const float*)d_in[17];
    const float* in_w   = (const float*)d_in[18];
    const float* conv_w = (const float*)d_in[19];
    const float* conv_b = (const float*)d_in[20];
    const float* xproj  = (const float*)d_in[21];
    const float* dtw    = (const float*)d_in[22];
    const float* dtb    = (const float*)d_in[23];
    const float* A_logs = (const float*)d_in[24];
    const float* Ds     = (const float*)d_in[25];
    const float* on_g   = (const float*)d_in[26];
    const float* on_b   = (const float*)d_in[27];
    const float* out_w  = (const float*)d_in[28];
    const float* sc1    = (const float*)d_in[29];
    const float* sc2    = (const float*)d_in[30];
    const float* sc3    = (const float*)d_in[31];
    const float* sc4    = (const float*)d_in[32];
    const float* bn_g   = (const float*)d_in[33];
    const float* bn_b   = (const float*)d_in[34];

    AxialParams P;
    for(int i=0;i<3;i++){
        P.kh[i]=(const float*)d_in[1+5*i];
        P.kw[i]=(const float*)d_in[2+5*i];
        P.k3[i]=(const float*)d_in[3+5*i];
        P.g[i] =(const float*)d_in[4+5*i];
        P.b[i] =(const float*)d_in[5+5*i];
    }

    // ---- workspace layout (bytes); total ~118 MB ----
    char* base = (char*)d_ws;
    float*    Y0   = (float*)   (base + 0);            // 12,582,912 f32
    ushort_t* ZS   = (ushort_t*)(base + 12582912);     // bf16
    ushort_t* XC   = (ushort_t*)(base + 25165824);     // bf16
    ushort_t* XCT  = (ushort_t*)(base + 37748736);     // bf16
    ushort_t* XBb  = (ushort_t*)(base + 50331648);     // bf16 (16 B rows); early alias: XW
    ushort_t* XW   = (ushort_t*)(base + 50331648);     // alias (dead before k_xdbl writes)
    ushort_t* XCc  = (ushort_t*)(base + 62914560);     // bf16 (16 C rows)
    float*    DT   = (float*)   (base + 75497472);     // f32 (2 delta rows)
    ushort_t* CHS  = (ushort_t*)(base + 78643200);     // bf16
    float*    SD   = (float*)   (base + 91226112);     // f32
    ushort_t* Y1   = (ushort_t*)(base + 92798976);     // bf16
    ushort_t* Y2   = (ushort_t*)(base + 105381888);    // bf16 (end 117,964,800)
    ushort_t* Y2T  = XBb;                              // alias (XBb dead after scan3)

    float* out = (float*)d_out;

    k_axial    <<<768,   256, 0, stream>>>(x, Y0, P);
    k_lnproj   <<<384,   256, 0, stream>>>(Y0, ln_g, ln_b, in_w, XW, ZS);
    k_dwt      <<<1536,  256, 0, stream>>>(XW, conv_w, conv_b, XC, XCT);
    k_xdbl     <<<1536,  256, 0, stream>>>(XC, XCT, xproj, XBb, XCc, DT);
    k_scan1    <<<3072,  128, 0, stream>>>(XBb, DT, XC, XCT, dtw, dtb, A_logs, CHS, SD);
    k_scan2    <<<96,   1024, 0, stream>>>(A_logs, SD, CHS);
    k_scan3    <<<3072,  128, 0, stream>>>(XBb, XCc, DT, XC, XCT, dtw, dtb, A_logs, CHS, Y1, Y2);
    k_transpose<<<1536,  256, 0, stream>>>(Y2, Y2T);
    k_final    <<<384,   256, 0, stream>>>(Y1, Y2T, ZS, Y0, XC, Ds, on_g, on_b, out_w,
                                           sc1, sc2, sc3, bn_g, bn_b, out);
    k_branch4  <<<4096,  256, 0, stream>>>(x, sc4, bn_g, bn_b, out);
}